// Round 16
// baseline (974.371 us; speedup 1.0000x reference)
//
#include <hip/hip_runtime.h>
#include <stdint.h>
#include <math.h>

#define NN 12288
#define DD 128
#define KTOP 31
#define TCAND 64         // candidate set >= top-64 by bf16 key (R0-R15-verified margin)
#define CCAP 128         // compaction capacity
#define RPB 48           // rows per loop-block; grid = 256 = 1 block/CU
#define WPL 16           // waves per loop block (1024 threads -> 4 waves/SIMD)
#define NIT 24           // column iterations: 12288 / (WPL*32)

typedef __attribute__((ext_vector_type(8))) short bf16x8;
typedef __attribute__((ext_vector_type(4))) float f32x4;

__device__ __forceinline__ unsigned short f2bf(float x) {  // RNE, no NaN in our data
  unsigned int u = __float_as_uint(x);
  u += 0x7fffu + ((u >> 16) & 1u);
  return (unsigned short)(u >> 16);
}

__device__ __forceinline__ unsigned umed3(unsigned a, unsigned b, unsigned c) {
  unsigned d;
  asm("v_med3_u32 %0, %1, %2, %3" : "=v"(d) : "v"(a), "v"(b), "v"(c));
  return d;
}

#define PINS8(Lx, P) { \
  const unsigned p_ = (P); \
  _Pragma("unroll") \
  for (int i_ = 0; i_ < 7; ++i_) \
    Lx[i_] = umed3(p_, Lx[i_], Lx[i_ + 1]); \
  Lx[7] = Lx[7] > p_ ? Lx[7] : p_; }

#define LKEY(ACC, LX, COLBASE) { \
  _Pragma("unroll") \
  for (int r_ = 0; r_ < 4; ++r_) { \
    unsigned bf_ = f2bf((ACC)[r_]); \
    unsigned s_ = (bf_ & 0x8000u) ? 0u : bf_; \
    unsigned p_k = (s_ << 16) | (unsigned)((COLBASE) + quad * 4 + r_); \
    PINS8(LX, p_k) } }

// ---------------- Kernel 0: transpose W1,W2 ----------------
__global__ __launch_bounds__(128)
void wtrans_kernel(const float* __restrict__ W1, const float* __restrict__ W2,
                   float* __restrict__ W1T, float* __restrict__ W2T) {
  const int r = blockIdx.x, c = threadIdx.x;
  W1T[(size_t)c * DD + r] = W1[(size_t)r * DD + c];
  W2T[(size_t)c * DD + r] = W2[(size_t)r * DD + c];
}

// ---------------- Kernel 1: MLP + L2 normalize + output zero-fill ----------------
// R16: each block NT-zeros its own 16 output rows (192 f32x4/thread), 2 stores
// per k-iteration spread through both layers. mlp's store pipe was idle (writes
// only 15.7 MB); the mandatory 604 MB zero-stream now overlaps fp64 compute
// here instead of competing with simloop's load stream. Math byte-identical.
__global__ __launch_bounds__(256)
void mlp_norm_kernel(const float* __restrict__ feat,
                     const float* __restrict__ W1T, const float* __restrict__ b1,
                     const float* __restrict__ W2T, const float* __restrict__ b2,
                     double* __restrict__ hn64, unsigned short* __restrict__ hnb,
                     float* __restrict__ out) {
  __shared__ float  bufA[16][DD];    // 8 KB (f32 input, exact)
  __shared__ double bufB[16][DD];    // 16 KB
  __shared__ double bufC[16][DD];    // 16 KB
  __shared__ double mnorm[16];
  const int t = threadIdx.x;
  const int c = t & 127;
  const int g = t >> 7;
  const int row0 = blockIdx.x * 16 + g * 8;

  // this block's 16 output rows: 49152 f32x4, 192 per thread
  f32x4* outzb = (f32x4*)(out + (size_t)blockIdx.x * 16 * NN);
  const f32x4 zz = {0.0f, 0.0f, 0.0f, 0.0f};

  #pragma unroll
  for (int rr = 0; rr < 8; ++rr)
    bufA[g * 8 + rr][c] = feat[(size_t)(row0 + rr) * DD + c];
  __syncthreads();

  {
    double acc[8] = {0,0,0,0,0,0,0,0};
    for (int k = 0; k < DD; k += 4) {
      const int j = k >> 2;                       // 0..31
      __builtin_nontemporal_store(zz, &outzb[(j * 2) * 256 + t]);
      __builtin_nontemporal_store(zz, &outzb[(j * 2 + 1) * 256 + t]);
      double w0 = (double)W1T[(size_t)k * DD + c];
      double w1 = (double)W1T[(size_t)(k + 1) * DD + c];
      double w2 = (double)W1T[(size_t)(k + 2) * DD + c];
      double w3 = (double)W1T[(size_t)(k + 3) * DD + c];
      #pragma unroll
      for (int rr = 0; rr < 8; ++rr) {
        f32x4 a4 = *(const f32x4*)(&bufA[g * 8 + rr][k]);
        acc[rr] = fma(w0, (double)a4.x, acc[rr]);
        acc[rr] = fma(w1, (double)a4.y, acc[rr]);
        acc[rr] = fma(w2, (double)a4.z, acc[rr]);
        acc[rr] = fma(w3, (double)a4.w, acc[rr]);
      }
    }
    double bb = (double)b1[c];
    #pragma unroll
    for (int rr = 0; rr < 8; ++rr)
      bufB[g * 8 + rr][c] = fmax(acc[rr] + bb, 0.0);
  }
  __syncthreads();
  {
    double acc[8] = {0,0,0,0,0,0,0,0};
    for (int k = 0; k < DD; k += 2) {
      const int j = k >> 1;                       // 0..63
      __builtin_nontemporal_store(zz, &outzb[(64 + j * 2) * 256 + t]);
      __builtin_nontemporal_store(zz, &outzb[(64 + j * 2 + 1) * 256 + t]);
      double w0 = (double)W2T[(size_t)k * DD + c];
      double w1 = (double)W2T[(size_t)(k + 1) * DD + c];
      #pragma unroll
      for (int rr = 0; rr < 8; ++rr) {
        double2 a2 = *(const double2*)(&bufB[g * 8 + rr][k]);
        acc[rr] = fma(w0, a2.x, acc[rr]);
        acc[rr] = fma(w1, a2.y, acc[rr]);
      }
    }
    double bb = (double)b2[c];
    #pragma unroll
    for (int rr = 0; rr < 8; ++rr)
      bufC[g * 8 + rr][c] = acc[rr] + bb;
  }
  __syncthreads();

  const int lane = t & 63;
  const int w = t >> 6;
  #pragma unroll
  for (int r2 = 0; r2 < 4; ++r2) {
    int rr = w * 4 + r2;
    double x0 = bufC[rr][lane];
    double x1 = bufC[rr][lane + 64];
    double s = x0 * x0 + x1 * x1;
    #pragma unroll
    for (int d = 1; d < 64; d <<= 1)
      s += __shfl_xor(s, d);
    if (lane == 0) mnorm[rr] = fmax(sqrt(s), 1e-12);
  }
  __syncthreads();
  #pragma unroll
  for (int rr = 0; rr < 8; ++rr) {
    double v = bufC[g * 8 + rr][c] / mnorm[g * 8 + rr];
    hn64[(size_t)(row0 + rr) * DD + c] = v;
    hnb[(size_t)(row0 + rr) * DD + c] = f2bf((float)v);
  }
}

// ---------------- Kernel 2: sim MFMA loop + ladders; keys -> row prefix (NO zero stores) ----------------
// R16: the zero-fill moved to mlp (previous kernel) -> this loop is pure
// loads+MFMA+ladder+key-dump. Zero->key ordering is the kernel boundary, so
// the old pre-dump vmcnt(0)+barrier is gone too. Stagger kept (R14).
__global__ __launch_bounds__(1024)
void simloop_kernel(const unsigned short* __restrict__ hnb,
                    float* __restrict__ out) {
  const int t = threadIdx.x, lane = t & 63, wv = t >> 6;   // wv 0..15
  const int m = lane & 15, quad = lane >> 4;
  const int row0 = blockIdx.x * RPB;
  const int it0 = (int)(((blockIdx.x >> 3) * 3u) % NIT);   // same-XCD phase spread

  bf16x8 af0[4], af1[4], af2[4];
  #pragma unroll
  for (int kc = 0; kc < 4; ++kc) {
    af0[kc] = *(const bf16x8*)(hnb + (size_t)(row0 + m) * DD + kc * 32 + quad * 8);
    af1[kc] = *(const bf16x8*)(hnb + (size_t)(row0 + 16 + m) * DD + kc * 32 + quad * 8);
    af2[kc] = *(const bf16x8*)(hnb + (size_t)(row0 + 32 + m) * DD + kc * 32 + quad * 8);
  }

  unsigned LA0[8] = {0,0,0,0,0,0,0,0}, LB0[8] = {0,0,0,0,0,0,0,0};
  unsigned LA1[8] = {0,0,0,0,0,0,0,0}, LB1[8] = {0,0,0,0,0,0,0,0};
  unsigned LA2[8] = {0,0,0,0,0,0,0,0}, LB2[8] = {0,0,0,0,0,0,0,0};

  for (int itt = 0; itt < NIT; ++itt) {
    int it = itt + it0; if (it >= NIT) it -= NIT;    // staggered column phase
    const int cb = it * (WPL * 32) + wv * 32;
    f32x4 a00 = {0,0,0,0}, a01 = {0,0,0,0};
    f32x4 a10 = {0,0,0,0}, a11 = {0,0,0,0};
    f32x4 a20 = {0,0,0,0}, a21 = {0,0,0,0};
    #pragma unroll
    for (int kc = 0; kc < 4; ++kc) {    // per-kc B loads: caps VGPR for 16-wave block
      bf16x8 b0 = *(const bf16x8*)(hnb + (size_t)(cb + m) * DD + kc * 32 + quad * 8);
      bf16x8 b1 = *(const bf16x8*)(hnb + (size_t)(cb + 16 + m) * DD + kc * 32 + quad * 8);
      a00 = __builtin_amdgcn_mfma_f32_16x16x32_bf16(b0, af0[kc], a00, 0, 0, 0);
      a01 = __builtin_amdgcn_mfma_f32_16x16x32_bf16(b1, af0[kc], a01, 0, 0, 0);
      a10 = __builtin_amdgcn_mfma_f32_16x16x32_bf16(b0, af1[kc], a10, 0, 0, 0);
      a11 = __builtin_amdgcn_mfma_f32_16x16x32_bf16(b1, af1[kc], a11, 0, 0, 0);
      a20 = __builtin_amdgcn_mfma_f32_16x16x32_bf16(b0, af2[kc], a20, 0, 0, 0);
      a21 = __builtin_amdgcn_mfma_f32_16x16x32_bf16(b1, af2[kc], a21, 0, 0, 0);
    }
    LKEY(a00, LA0, cb)      LKEY(a01, LB0, cb + 16)
    LKEY(a10, LA1, cb)      LKEY(a11, LB1, cb + 16)
    LKEY(a20, LA2, cb)      LKEY(a21, LB2, cb + 16)
  }

  // key dump into row output prefixes (zeros written by mlp kernel; boundary
  // ordering guarantees they landed). Register-only producer -> no barrier.
  const int sbase = (wv * 4 + quad) * 16;   // 64 slots x 16 u32 = 1024 keys/row
  {
    unsigned* d0 = (unsigned*)(out + (size_t)(row0 + m) * NN) + sbase;
    *(uint4*)(d0)     = make_uint4(LA0[0], LA0[1], LA0[2], LA0[3]);
    *(uint4*)(d0 + 4) = make_uint4(LA0[4], LA0[5], LA0[6], LA0[7]);
    *(uint4*)(d0 + 8) = make_uint4(LB0[0], LB0[1], LB0[2], LB0[3]);
    *(uint4*)(d0 + 12)= make_uint4(LB0[4], LB0[5], LB0[6], LB0[7]);
    unsigned* d1 = (unsigned*)(out + (size_t)(row0 + 16 + m) * NN) + sbase;
    *(uint4*)(d1)     = make_uint4(LA1[0], LA1[1], LA1[2], LA1[3]);
    *(uint4*)(d1 + 4) = make_uint4(LA1[4], LA1[5], LA1[6], LA1[7]);
    *(uint4*)(d1 + 8) = make_uint4(LB1[0], LB1[1], LB1[2], LB1[3]);
    *(uint4*)(d1 + 12)= make_uint4(LB1[4], LB1[5], LB1[6], LB1[7]);
    unsigned* d2 = (unsigned*)(out + (size_t)(row0 + 32 + m) * NN) + sbase;
    *(uint4*)(d2)     = make_uint4(LA2[0], LA2[1], LA2[2], LA2[3]);
    *(uint4*)(d2 + 4) = make_uint4(LA2[4], LA2[5], LA2[6], LA2[7]);
    *(uint4*)(d2 + 8) = make_uint4(LB2[0], LB2[1], LB2[2], LB2[3]);
    *(uint4*)(d2 + 12)= make_uint4(LB2[4], LB2[5], LB2[6], LB2[7]);
  }
}

// ---------------- Kernel 3: select + fp64 rescore + top-31 + prefix-zero + scatter ----------------
// Byte-identical to R14 (8 candidates in flight).
__global__ __launch_bounds__(256)
void select_kernel(const double* __restrict__ hn64, float* __restrict__ out) {
  __shared__ unsigned scand[4][CCAP];
  __shared__ double cres[4][CCAP];
  const int t = threadIdx.x, lane = t & 63, wv = t >> 6;
  const int row = blockIdx.x * 4 + wv;
  float* orow = out + (size_t)row * NN;

  unsigned k16[16];
  {
    const unsigned* src = (const unsigned*)orow + lane * 16;
    #pragma unroll
    for (int q = 0; q < 4; ++q) {
      uint4 a = *(const uint4*)(src + q * 4);
      k16[q * 4 + 0] = a.x; k16[q * 4 + 1] = a.y;
      k16[q * 4 + 2] = a.z; k16[q * 4 + 3] = a.w;
    }
  }

  unsigned lo = 0, hi = 0xFFFFu;
  while (lo < hi) {
    unsigned mid = (lo + hi + 1) >> 1;
    int c = 0;
    #pragma unroll
    for (int i = 0; i < 16; ++i) c += (int)((k16[i] >> 16) >= mid);
    #pragma unroll
    for (int d = 1; d < 64; d <<= 1) c += __shfl_xor(c, d);
    if (c >= TCAND) lo = mid; else hi = mid - 1;
  }
  const unsigned thr = lo;

  int cl = 0;
  #pragma unroll
  for (int i = 0; i < 16; ++i) cl += (int)((k16[i] >> 16) >= thr);
  int pre = cl;
  #pragma unroll
  for (int d = 1; d < 64; d <<= 1) {
    int y = __shfl_up(pre, d);
    if (lane >= d) pre += y;
  }
  const int total = __shfl(pre, 63);
  const int nc = total < CCAP ? total : CCAP;
  int slot = pre - cl;
  #pragma unroll
  for (int i = 0; i < 16; ++i) {
    if ((k16[i] >> 16) >= thr) {
      if (slot < CCAP) scand[wv][slot] = k16[i];
      ++slot;
    }
  }
  // same-wave LDS producer->consumer: compiler inserts lgkmcnt

  // phase 3: 8-candidate-in-flight coalesced fp64 rescore
  const double* arow = hn64 + (size_t)row * DD;
  const int g4 = lane >> 4;          // candidate group (0..3)
  const int kl = (lane & 15) * 8;    // this lane's 8-double chunk (64 B line)
  double a[8];
  #pragma unroll
  for (int i = 0; i < 8; ++i) a[i] = arow[kl + i];
  const int ng = (nc + 7) >> 3;      // 2 candidates per group per iteration
  for (int g = 0; g < ng; ++g) {
    const int ci0 = 8 * g + g4;
    const int ci1 = ci0 + 4;
    double p0 = 0.0, p1 = 0.0;
    if (ci0 < nc) {
      const int col = (int)(scand[wv][ci0] & 0xFFFFu);
      const double* brow = hn64 + (size_t)col * DD + kl;
      double2 b01 = *(const double2*)(brow);
      double2 b23 = *(const double2*)(brow + 2);
      double2 b45 = *(const double2*)(brow + 4);
      double2 b67 = *(const double2*)(brow + 6);
      p0 = fma(a[0], b01.x, fma(a[1], b01.y, fma(a[2], b23.x, a[3] * b23.y)));
      p0 = fma(a[4], b45.x, fma(a[5], b45.y, fma(a[6], b67.x, fma(a[7], b67.y, p0))));
    }
    if (ci1 < nc) {
      const int col = (int)(scand[wv][ci1] & 0xFFFFu);
      const double* brow = hn64 + (size_t)col * DD + kl;
      double2 b01 = *(const double2*)(brow);
      double2 b23 = *(const double2*)(brow + 2);
      double2 b45 = *(const double2*)(brow + 4);
      double2 b67 = *(const double2*)(brow + 6);
      p1 = fma(a[0], b01.x, fma(a[1], b01.y, fma(a[2], b23.x, a[3] * b23.y)));
      p1 = fma(a[4], b45.x, fma(a[5], b45.y, fma(a[6], b67.x, fma(a[7], b67.y, p1))));
    }
    #pragma unroll
    for (int d = 1; d < 16; d <<= 1) {
      p0 += __shfl_xor(p0, d);
      p1 += __shfl_xor(p1, d);
    }
    if ((lane & 15) == 0) {
      if (ci0 < nc) cres[wv][ci0] = p0;
      if (ci1 < nc) cres[wv][ci1] = p1;
    }
  }
  double rv0 = -1.0e300, rv1 = -1.0e300;
  int rc0 = 0x7fffffff, rc1 = 0x7fffffff;
  if (lane < nc)      { rv0 = cres[wv][lane];      rc0 = (int)(scand[wv][lane] & 0xFFFFu); }
  if (lane + 64 < nc) { rv1 = cres[wv][lane + 64]; rc1 = (int)(scand[wv][lane + 64] & 0xFFFFu); }

  float fkv = 0.0f; int fkc = 0;
  for (int itk = 0; itk < KTOP; ++itk) {
    bool f = (rv0 > rv1) || (rv0 == rv1 && rc0 < rc1);
    double bv = f ? rv0 : rv1;
    int bc = f ? rc0 : rc1;
    #pragma unroll
    for (int d = 1; d < 64; d <<= 1) {
      double ov = __shfl_xor(bv, d);
      int    oc = __shfl_xor(bc, d);
      bool tk = (ov > bv) || (ov == bv && oc < bc);
      bv = tk ? ov : bv;
      bc = tk ? oc : bc;
    }
    if (lane == itk) { fkv = (float)fmax(bv, 0.0); fkc = bc; }
    if (rv0 == bv && rc0 == bc) rv0 = -1.0e300;
    else if (rv1 == bv && rc1 == bc) rv1 = -1.0e300;
  }

  // re-zero this row's 4 KB key prefix (cols 0-1023), drain, scatter
  {
    f32x4* zp = (f32x4*)orow;
    const f32x4 z = {0.0f, 0.0f, 0.0f, 0.0f};
    #pragma unroll
    for (int j = 0; j < 4; ++j)
      __builtin_nontemporal_store(z, &zp[j * 64 + lane]);
  }
  asm volatile("s_waitcnt vmcnt(0)" ::: "memory");
  if (lane < KTOP) orow[fkc] = fkv;
}

extern "C" void kernel_launch(void* const* d_in, const int* in_sizes, int n_in,
                              void* d_out, int out_size, void* d_ws, size_t ws_size,
                              hipStream_t stream) {
  const float* feat = (const float*)d_in[0];
  const float* W1 = (const float*)d_in[1];
  const float* b1 = (const float*)d_in[2];
  const float* W2 = (const float*)d_in[3];
  const float* b2 = (const float*)d_in[4];
  float* out = (float*)d_out;

  // ws: hn64 (12.6 MB) | hnb (3.1 MB) | W1T,W2T (128 KB)
  double* hn64 = (double*)d_ws;
  unsigned short* hnb = (unsigned short*)(hn64 + (size_t)NN * DD);
  float* W1T = (float*)(hnb + (size_t)NN * DD);
  float* W2T = W1T + DD * DD;

  wtrans_kernel<<<DD, DD, 0, stream>>>(W1, W2, W1T, W2T);
  mlp_norm_kernel<<<NN / 16, 256, 0, stream>>>(feat, W1T, b1, W2T, b2, hn64, hnb, out);
  simloop_kernel<<<NN / RPB, 1024, 0, stream>>>(hnb, out);
  select_kernel<<<NN / 4, 256, 0, stream>>>(hn64, out);
}

// Round 17
// 884.076 us; speedup vs baseline: 1.1021x; 1.1021x over previous
//
#include <hip/hip_runtime.h>
#include <stdint.h>
#include <math.h>

#define NN 12288
#define DD 128
#define KTOP 31
#define TCAND 64         // candidate set >= top-64 by bf16 key (R0-R13-verified margin)
#define CCAP 128         // compaction capacity
#define RPB 48           // rows per loop-block; grid = 256 = 1 block/CU
#define WPL 16           // waves per loop block (1024 threads -> 4 waves/SIMD)
#define NIT 24           // column iterations: 12288 / (WPL*32)
#define KPROW 1024       // keys per row (128 streams x depth 8); 4 KB = row output prefix

typedef __attribute__((ext_vector_type(8))) short bf16x8;
typedef __attribute__((ext_vector_type(4))) float f32x4;

__device__ __forceinline__ unsigned short f2bf(float x) {  // RNE, no NaN in our data
  unsigned int u = __float_as_uint(x);
  u += 0x7fffu + ((u >> 16) & 1u);
  return (unsigned short)(u >> 16);
}

__device__ __forceinline__ unsigned umed3(unsigned a, unsigned b, unsigned c) {
  unsigned d;
  asm("v_med3_u32 %0, %1, %2, %3" : "=v"(d) : "v"(a), "v"(b), "v"(c));
  return d;
}

#define PINS8(Lx, P) { \
  const unsigned p_ = (P); \
  _Pragma("unroll") \
  for (int i_ = 0; i_ < 7; ++i_) \
    Lx[i_] = umed3(p_, Lx[i_], Lx[i_ + 1]); \
  Lx[7] = Lx[7] > p_ ? Lx[7] : p_; }

#define LKEY(ACC, LX, COLBASE) { \
  _Pragma("unroll") \
  for (int r_ = 0; r_ < 4; ++r_) { \
    unsigned bf_ = f2bf((ACC)[r_]); \
    unsigned s_ = (bf_ & 0x8000u) ? 0u : bf_; \
    unsigned p_k = (s_ << 16) | (unsigned)((COLBASE) + quad * 4 + r_); \
    PINS8(LX, p_k) } }

// ---------------- Kernel 0: transpose W1,W2 ----------------
__global__ __launch_bounds__(128)
void wtrans_kernel(const float* __restrict__ W1, const float* __restrict__ W2,
                   float* __restrict__ W1T, float* __restrict__ W2T) {
  const int r = blockIdx.x, c = threadIdx.x;
  W1T[(size_t)c * DD + r] = W1[(size_t)r * DD + c];
  W2T[(size_t)c * DD + r] = W2[(size_t)r * DD + c];
}

// ---------------- Kernel 1: MLP + L2 normalize (byte-identical to R12/R13/R14) ----------------
__global__ __launch_bounds__(256)
void mlp_norm_kernel(const float* __restrict__ feat,
                     const float* __restrict__ W1T, const float* __restrict__ b1,
                     const float* __restrict__ W2T, const float* __restrict__ b2,
                     double* __restrict__ hn64, unsigned short* __restrict__ hnb) {
  __shared__ float  bufA[16][DD];    // 8 KB (f32 input, exact)
  __shared__ double bufB[16][DD];    // 16 KB
  __shared__ double bufC[16][DD];    // 16 KB
  __shared__ double mnorm[16];
  const int t = threadIdx.x;
  const int c = t & 127;
  const int g = t >> 7;
  const int row0 = blockIdx.x * 16 + g * 8;

  #pragma unroll
  for (int rr = 0; rr < 8; ++rr)
    bufA[g * 8 + rr][c] = feat[(size_t)(row0 + rr) * DD + c];
  __syncthreads();

  {
    double acc[8] = {0,0,0,0,0,0,0,0};
    for (int k = 0; k < DD; k += 4) {
      double w0 = (double)W1T[(size_t)k * DD + c];
      double w1 = (double)W1T[(size_t)(k + 1) * DD + c];
      double w2 = (double)W1T[(size_t)(k + 2) * DD + c];
      double w3 = (double)W1T[(size_t)(k + 3) * DD + c];
      #pragma unroll
      for (int rr = 0; rr < 8; ++rr) {
        f32x4 a4 = *(const f32x4*)(&bufA[g * 8 + rr][k]);
        acc[rr] = fma(w0, (double)a4.x, acc[rr]);
        acc[rr] = fma(w1, (double)a4.y, acc[rr]);
        acc[rr] = fma(w2, (double)a4.z, acc[rr]);
        acc[rr] = fma(w3, (double)a4.w, acc[rr]);
      }
    }
    double bb = (double)b1[c];
    #pragma unroll
    for (int rr = 0; rr < 8; ++rr)
      bufB[g * 8 + rr][c] = fmax(acc[rr] + bb, 0.0);
  }
  __syncthreads();
  {
    double acc[8] = {0,0,0,0,0,0,0,0};
    for (int k = 0; k < DD; k += 2) {
      double w0 = (double)W2T[(size_t)k * DD + c];
      double w1 = (double)W2T[(size_t)(k + 1) * DD + c];
      #pragma unroll
      for (int rr = 0; rr < 8; ++rr) {
        double2 a2 = *(const double2*)(&bufB[g * 8 + rr][k]);
        acc[rr] = fma(w0, a2.x, acc[rr]);
        acc[rr] = fma(w1, a2.y, acc[rr]);
      }
    }
    double bb = (double)b2[c];
    #pragma unroll
    for (int rr = 0; rr < 8; ++rr)
      bufC[g * 8 + rr][c] = acc[rr] + bb;
  }
  __syncthreads();

  const int lane = t & 63;
  const int w = t >> 6;
  #pragma unroll
  for (int r2 = 0; r2 < 4; ++r2) {
    int rr = w * 4 + r2;
    double x0 = bufC[rr][lane];
    double x1 = bufC[rr][lane + 64];
    double s = x0 * x0 + x1 * x1;
    #pragma unroll
    for (int d = 1; d < 64; d <<= 1)
      s += __shfl_xor(s, d);
    if (lane == 0) mnorm[rr] = fmax(sqrt(s), 1e-12);
  }
  __syncthreads();
  #pragma unroll
  for (int rr = 0; rr < 8; ++rr) {
    double v = bufC[g * 8 + rr][c] / mnorm[g * 8 + rr];
    hn64[(size_t)(row0 + rr) * DD + c] = v;
    hnb[(size_t)(row0 + rr) * DD + c] = f2bf((float)v);
  }
}

// ---------------- Kernel 2: sim MFMA loop + ladders + in-loop zeros; keys -> row prefix ----------------
// In-loop NT zeros are safe HERE (unlike mlp, R16 lesson): the MFMA consumes
// its loads before the stores issue in program order, and the ladder VALU
// gives the store stream slack — no load-wait ever drains stores.
// Stagger (R14): same-XCD blocks start at 8 different column phases.
__global__ __launch_bounds__(1024)
void simloop_kernel(const unsigned short* __restrict__ hnb,
                    float* __restrict__ out) {
  const int t = threadIdx.x, lane = t & 63, wv = t >> 6;   // wv 0..15
  const int m = lane & 15, quad = lane >> 4;
  const int row0 = blockIdx.x * RPB;
  const int it0 = (int)(((blockIdx.x >> 3) * 3u) % NIT);   // same-XCD phase spread

  bf16x8 af0[4], af1[4], af2[4];
  #pragma unroll
  for (int kc = 0; kc < 4; ++kc) {
    af0[kc] = *(const bf16x8*)(hnb + (size_t)(row0 + m) * DD + kc * 32 + quad * 8);
    af1[kc] = *(const bf16x8*)(hnb + (size_t)(row0 + 16 + m) * DD + kc * 32 + quad * 8);
    af2[kc] = *(const bf16x8*)(hnb + (size_t)(row0 + 32 + m) * DD + kc * 32 + quad * 8);
  }

  unsigned LA0[8] = {0,0,0,0,0,0,0,0}, LB0[8] = {0,0,0,0,0,0,0,0};
  unsigned LA1[8] = {0,0,0,0,0,0,0,0}, LB1[8] = {0,0,0,0,0,0,0,0};
  unsigned LA2[8] = {0,0,0,0,0,0,0,0}, LB2[8] = {0,0,0,0,0,0,0,0};

  f32x4* outz = (f32x4*)(out + (size_t)row0 * NN);   // 48 rows = 147456 f32x4
  const f32x4 z = {0.0f, 0.0f, 0.0f, 0.0f};

  for (int itt = 0; itt < NIT; ++itt) {
    int it = itt + it0; if (it >= NIT) it -= NIT;    // staggered column phase
    const int cb = it * (WPL * 32) + wv * 32;
    f32x4 a00 = {0,0,0,0}, a01 = {0,0,0,0};
    f32x4 a10 = {0,0,0,0}, a11 = {0,0,0,0};
    f32x4 a20 = {0,0,0,0}, a21 = {0,0,0,0};
    #pragma unroll
    for (int kc = 0; kc < 4; ++kc) {    // per-kc B loads: caps VGPR for 16-wave block
      bf16x8 b0 = *(const bf16x8*)(hnb + (size_t)(cb + m) * DD + kc * 32 + quad * 8);
      bf16x8 b1 = *(const bf16x8*)(hnb + (size_t)(cb + 16 + m) * DD + kc * 32 + quad * 8);
      a00 = __builtin_amdgcn_mfma_f32_16x16x32_bf16(b0, af0[kc], a00, 0, 0, 0);
      a01 = __builtin_amdgcn_mfma_f32_16x16x32_bf16(b1, af0[kc], a01, 0, 0, 0);
      a10 = __builtin_amdgcn_mfma_f32_16x16x32_bf16(b0, af1[kc], a10, 0, 0, 0);
      a11 = __builtin_amdgcn_mfma_f32_16x16x32_bf16(b1, af1[kc], a11, 0, 0, 0);
      a20 = __builtin_amdgcn_mfma_f32_16x16x32_bf16(b0, af2[kc], a20, 0, 0, 0);
      a21 = __builtin_amdgcn_mfma_f32_16x16x32_bf16(b1, af2[kc], a21, 0, 0, 0);
    }
    // in-loop NT zeros: 48*NN f32 / 24 iters / 1024 thr = 6 f32x4 per thread
    #pragma unroll
    for (int j = 0; j < 6; ++j)
      __builtin_nontemporal_store(z, &outz[it * 6144 + j * 1024 + t]);
    LKEY(a00, LA0, cb)      LKEY(a01, LB0, cb + 16)
    LKEY(a10, LA1, cb)      LKEY(a11, LB1, cb + 16)
    LKEY(a20, LA2, cb)      LKEY(a21, LB2, cb + 16)
  }

  // all zeros of this block retired before key dump overwrites row prefixes
  asm volatile("s_waitcnt vmcnt(0)" ::: "memory");
  __syncthreads();

  const int sbase = (wv * 4 + quad) * 16;   // 64 slots x 16 u32 = 1024 keys/row
  {
    unsigned* d0 = (unsigned*)(out + (size_t)(row0 + m) * NN) + sbase;
    *(uint4*)(d0)     = make_uint4(LA0[0], LA0[1], LA0[2], LA0[3]);
    *(uint4*)(d0 + 4) = make_uint4(LA0[4], LA0[5], LA0[6], LA0[7]);
    *(uint4*)(d0 + 8) = make_uint4(LB0[0], LB0[1], LB0[2], LB0[3]);
    *(uint4*)(d0 + 12)= make_uint4(LB0[4], LB0[5], LB0[6], LB0[7]);
    unsigned* d1 = (unsigned*)(out + (size_t)(row0 + 16 + m) * NN) + sbase;
    *(uint4*)(d1)     = make_uint4(LA1[0], LA1[1], LA1[2], LA1[3]);
    *(uint4*)(d1 + 4) = make_uint4(LA1[4], LA1[5], LA1[6], LA1[7]);
    *(uint4*)(d1 + 8) = make_uint4(LB1[0], LB1[1], LB1[2], LB1[3]);
    *(uint4*)(d1 + 12)= make_uint4(LB1[4], LB1[5], LB1[6], LB1[7]);
    unsigned* d2 = (unsigned*)(out + (size_t)(row0 + 32 + m) * NN) + sbase;
    *(uint4*)(d2)     = make_uint4(LA2[0], LA2[1], LA2[2], LA2[3]);
    *(uint4*)(d2 + 4) = make_uint4(LA2[4], LA2[5], LA2[6], LA2[7]);
    *(uint4*)(d2 + 8) = make_uint4(LB2[0], LB2[1], LB2[2], LB2[3]);
    *(uint4*)(d2 + 12)= make_uint4(LB2[4], LB2[5], LB2[6], LB2[7]);
  }
}

// ---------------- Kernel 3: select + fp64 rescore + top-31 + prefix-zero + scatter ----------------
// 8 candidates in flight (R13+R14 lever, verified).
__global__ __launch_bounds__(256)
void select_kernel(const double* __restrict__ hn64, float* __restrict__ out) {
  __shared__ unsigned scand[4][CCAP];
  __shared__ double cres[4][CCAP];
  const int t = threadIdx.x, lane = t & 63, wv = t >> 6;
  const int row = blockIdx.x * 4 + wv;
  float* orow = out + (size_t)row * NN;

  unsigned k16[16];
  {
    const unsigned* src = (const unsigned*)orow + lane * 16;
    #pragma unroll
    for (int q = 0; q < 4; ++q) {
      uint4 a = *(const uint4*)(src + q * 4);
      k16[q * 4 + 0] = a.x; k16[q * 4 + 1] = a.y;
      k16[q * 4 + 2] = a.z; k16[q * 4 + 3] = a.w;
    }
  }

  unsigned lo = 0, hi = 0xFFFFu;
  while (lo < hi) {
    unsigned mid = (lo + hi + 1) >> 1;
    int c = 0;
    #pragma unroll
    for (int i = 0; i < 16; ++i) c += (int)((k16[i] >> 16) >= mid);
    #pragma unroll
    for (int d = 1; d < 64; d <<= 1) c += __shfl_xor(c, d);
    if (c >= TCAND) lo = mid; else hi = mid - 1;
  }
  const unsigned thr = lo;

  int cl = 0;
  #pragma unroll
  for (int i = 0; i < 16; ++i) cl += (int)((k16[i] >> 16) >= thr);
  int pre = cl;
  #pragma unroll
  for (int d = 1; d < 64; d <<= 1) {
    int y = __shfl_up(pre, d);
    if (lane >= d) pre += y;
  }
  const int total = __shfl(pre, 63);
  const int nc = total < CCAP ? total : CCAP;
  int slot = pre - cl;
  #pragma unroll
  for (int i = 0; i < 16; ++i) {
    if ((k16[i] >> 16) >= thr) {
      if (slot < CCAP) scand[wv][slot] = k16[i];
      ++slot;
    }
  }
  // same-wave LDS producer->consumer: compiler inserts lgkmcnt

  // phase 3: 8-candidate-in-flight coalesced fp64 rescore
  const double* arow = hn64 + (size_t)row * DD;
  const int g4 = lane >> 4;          // candidate group (0..3)
  const int kl = (lane & 15) * 8;    // this lane's 8-double chunk (64 B line)
  double a[8];
  #pragma unroll
  for (int i = 0; i < 8; ++i) a[i] = arow[kl + i];
  const int ng = (nc + 7) >> 3;      // 2 candidates per group per iteration
  for (int g = 0; g < ng; ++g) {
    const int ci0 = 8 * g + g4;
    const int ci1 = ci0 + 4;
    double p0 = 0.0, p1 = 0.0;
    if (ci0 < nc) {
      const int col = (int)(scand[wv][ci0] & 0xFFFFu);
      const double* brow = hn64 + (size_t)col * DD + kl;
      double2 b01 = *(const double2*)(brow);
      double2 b23 = *(const double2*)(brow + 2);
      double2 b45 = *(const double2*)(brow + 4);
      double2 b67 = *(const double2*)(brow + 6);
      p0 = fma(a[0], b01.x, fma(a[1], b01.y, fma(a[2], b23.x, a[3] * b23.y)));
      p0 = fma(a[4], b45.x, fma(a[5], b45.y, fma(a[6], b67.x, fma(a[7], b67.y, p0))));
    }
    if (ci1 < nc) {
      const int col = (int)(scand[wv][ci1] & 0xFFFFu);
      const double* brow = hn64 + (size_t)col * DD + kl;
      double2 b01 = *(const double2*)(brow);
      double2 b23 = *(const double2*)(brow + 2);
      double2 b45 = *(const double2*)(brow + 4);
      double2 b67 = *(const double2*)(brow + 6);
      p1 = fma(a[0], b01.x, fma(a[1], b01.y, fma(a[2], b23.x, a[3] * b23.y)));
      p1 = fma(a[4], b45.x, fma(a[5], b45.y, fma(a[6], b67.x, fma(a[7], b67.y, p1))));
    }
    #pragma unroll
    for (int d = 1; d < 16; d <<= 1) {
      p0 += __shfl_xor(p0, d);
      p1 += __shfl_xor(p1, d);
    }
    if ((lane & 15) == 0) {
      if (ci0 < nc) cres[wv][ci0] = p0;
      if (ci1 < nc) cres[wv][ci1] = p1;
    }
  }
  double rv0 = -1.0e300, rv1 = -1.0e300;
  int rc0 = 0x7fffffff, rc1 = 0x7fffffff;
  if (lane < nc)      { rv0 = cres[wv][lane];      rc0 = (int)(scand[wv][lane] & 0xFFFFu); }
  if (lane + 64 < nc) { rv1 = cres[wv][lane + 64]; rc1 = (int)(scand[wv][lane + 64] & 0xFFFFu); }

  float fkv = 0.0f; int fkc = 0;
  for (int itk = 0; itk < KTOP; ++itk) {
    bool f = (rv0 > rv1) || (rv0 == rv1 && rc0 < rc1);
    double bv = f ? rv0 : rv1;
    int bc = f ? rc0 : rc1;
    #pragma unroll
    for (int d = 1; d < 64; d <<= 1) {
      double ov = __shfl_xor(bv, d);
      int    oc = __shfl_xor(bc, d);
      bool tk = (ov > bv) || (ov == bv && oc < bc);
      bv = tk ? ov : bv;
      bc = tk ? oc : bc;
    }
    if (lane == itk) { fkv = (float)fmax(bv, 0.0); fkc = bc; }
    if (rv0 == bv && rc0 == bc) rv0 = -1.0e300;
    else if (rv1 == bv && rc1 == bc) rv1 = -1.0e300;
  }

  // re-zero this row's 4 KB key prefix (cols 0-1023), drain, scatter
  {
    f32x4* zp = (f32x4*)orow;
    const f32x4 z = {0.0f, 0.0f, 0.0f, 0.0f};
    #pragma unroll
    for (int j = 0; j < 4; ++j)
      __builtin_nontemporal_store(z, &zp[j * 64 + lane]);
  }
  asm volatile("s_waitcnt vmcnt(0)" ::: "memory");
  if (lane < KTOP) orow[fkc] = fkv;
}

extern "C" void kernel_launch(void* const* d_in, const int* in_sizes, int n_in,
                              void* d_out, int out_size, void* d_ws, size_t ws_size,
                              hipStream_t stream) {
  const float* feat = (const float*)d_in[0];
  const float* W1 = (const float*)d_in[1];
  const float* b1 = (const float*)d_in[2];
  const float* W2 = (const float*)d_in[3];
  const float* b2 = (const float*)d_in[4];
  float* out = (float*)d_out;

  // ws: hn64 (12.6 MB) | hnb (3.1 MB) | W1T,W2T (128 KB)
  double* hn64 = (double*)d_ws;
  unsigned short* hnb = (unsigned short*)(hn64 + (size_t)NN * DD);
  float* W1T = (float*)(hnb + (size_t)NN * DD);
  float* W2T = W1T + DD * DD;

  wtrans_kernel<<<DD, DD, 0, stream>>>(W1, W2, W1T, W2T);
  mlp_norm_kernel<<<NN / 16, 256, 0, stream>>>(feat, W1T, b1, W2T, b2, hn64, hnb);
  simloop_kernel<<<NN / RPB, 1024, 0, stream>>>(hnb, out);
  select_kernel<<<NN / 4, 256, 0, stream>>>(hn64, out);
}

// Round 18
// 876.339 us; speedup vs baseline: 1.1119x; 1.0088x over previous
//
#include <hip/hip_runtime.h>
#include <stdint.h>
#include <math.h>

#define NN 12288
#define DD 128
#define KTOP 31
#define TCAND 64         // candidate set >= top-64 by bf16 key (R0-R17-verified margin)
#define CCAP 128         // compaction capacity
#define RPB 48           // rows per loop-block; grid = 256 = 1 block/CU
#define WPL 16           // waves per loop block (1024 threads -> 4 waves/SIMD)
#define NIT 24           // column iterations: 12288 / (WPL*32)
#define KPROW 1024       // keys per row (128 streams x depth 8); 4 KB = row output prefix

typedef __attribute__((ext_vector_type(8))) short bf16x8;
typedef __attribute__((ext_vector_type(4))) float f32x4;

__device__ __forceinline__ unsigned short f2bf(float x) {  // RNE, no NaN in our data
  unsigned int u = __float_as_uint(x);
  u += 0x7fffu + ((u >> 16) & 1u);
  return (unsigned short)(u >> 16);
}

__device__ __forceinline__ unsigned umed3(unsigned a, unsigned b, unsigned c) {
  unsigned d;
  asm("v_med3_u32 %0, %1, %2, %3" : "=v"(d) : "v"(a), "v"(b), "v"(c));
  return d;
}

#define PINS8(Lx, P) { \
  const unsigned p_ = (P); \
  _Pragma("unroll") \
  for (int i_ = 0; i_ < 7; ++i_) \
    Lx[i_] = umed3(p_, Lx[i_], Lx[i_ + 1]); \
  Lx[7] = Lx[7] > p_ ? Lx[7] : p_; }

#define LKEY(ACC, LX, COLBASE) { \
  _Pragma("unroll") \
  for (int r_ = 0; r_ < 4; ++r_) { \
    unsigned bf_ = f2bf((ACC)[r_]); \
    unsigned s_ = (bf_ & 0x8000u) ? 0u : bf_; \
    unsigned p_k = (s_ << 16) | (unsigned)((COLBASE) + quad * 4 + r_); \
    PINS8(LX, p_k) } }

// ---------------- Kernel 0: transpose W1,W2 ----------------
__global__ __launch_bounds__(128)
void wtrans_kernel(const float* __restrict__ W1, const float* __restrict__ W2,
                   float* __restrict__ W1T, float* __restrict__ W2T) {
  const int r = blockIdx.x, c = threadIdx.x;
  W1T[(size_t)c * DD + r] = W1[(size_t)r * DD + c];
  W2T[(size_t)c * DD + r] = W2[(size_t)r * DD + c];
}

// ---------------- Kernel 1: MLP + L2 normalize ----------------
// R18: normalized vectors stored as fp32 (hnf) instead of fp64. Internal math
// byte-identical (fp64 FMA chain, fp64 norm); only the store type changes.
// hnb = f2bf((float)v) is unchanged -> bf16 keys bit-identical to R17.
__global__ __launch_bounds__(256)
void mlp_norm_kernel(const float* __restrict__ feat,
                     const float* __restrict__ W1T, const float* __restrict__ b1,
                     const float* __restrict__ W2T, const float* __restrict__ b2,
                     float* __restrict__ hnf, unsigned short* __restrict__ hnb) {
  __shared__ float  bufA[16][DD];    // 8 KB (f32 input, exact)
  __shared__ double bufB[16][DD];    // 16 KB
  __shared__ double bufC[16][DD];    // 16 KB
  __shared__ double mnorm[16];
  const int t = threadIdx.x;
  const int c = t & 127;
  const int g = t >> 7;
  const int row0 = blockIdx.x * 16 + g * 8;

  #pragma unroll
  for (int rr = 0; rr < 8; ++rr)
    bufA[g * 8 + rr][c] = feat[(size_t)(row0 + rr) * DD + c];
  __syncthreads();

  {
    double acc[8] = {0,0,0,0,0,0,0,0};
    for (int k = 0; k < DD; k += 4) {
      double w0 = (double)W1T[(size_t)k * DD + c];
      double w1 = (double)W1T[(size_t)(k + 1) * DD + c];
      double w2 = (double)W1T[(size_t)(k + 2) * DD + c];
      double w3 = (double)W1T[(size_t)(k + 3) * DD + c];
      #pragma unroll
      for (int rr = 0; rr < 8; ++rr) {
        f32x4 a4 = *(const f32x4*)(&bufA[g * 8 + rr][k]);
        acc[rr] = fma(w0, (double)a4.x, acc[rr]);
        acc[rr] = fma(w1, (double)a4.y, acc[rr]);
        acc[rr] = fma(w2, (double)a4.z, acc[rr]);
        acc[rr] = fma(w3, (double)a4.w, acc[rr]);
      }
    }
    double bb = (double)b1[c];
    #pragma unroll
    for (int rr = 0; rr < 8; ++rr)
      bufB[g * 8 + rr][c] = fmax(acc[rr] + bb, 0.0);
  }
  __syncthreads();
  {
    double acc[8] = {0,0,0,0,0,0,0,0};
    for (int k = 0; k < DD; k += 2) {
      double w0 = (double)W2T[(size_t)k * DD + c];
      double w1 = (double)W2T[(size_t)(k + 1) * DD + c];
      #pragma unroll
      for (int rr = 0; rr < 8; ++rr) {
        double2 a2 = *(const double2*)(&bufB[g * 8 + rr][k]);
        acc[rr] = fma(w0, a2.x, acc[rr]);
        acc[rr] = fma(w1, a2.y, acc[rr]);
      }
    }
    double bb = (double)b2[c];
    #pragma unroll
    for (int rr = 0; rr < 8; ++rr)
      bufC[g * 8 + rr][c] = acc[rr] + bb;
  }
  __syncthreads();

  const int lane = t & 63;
  const int w = t >> 6;
  #pragma unroll
  for (int r2 = 0; r2 < 4; ++r2) {
    int rr = w * 4 + r2;
    double x0 = bufC[rr][lane];
    double x1 = bufC[rr][lane + 64];
    double s = x0 * x0 + x1 * x1;
    #pragma unroll
    for (int d = 1; d < 64; d <<= 1)
      s += __shfl_xor(s, d);
    if (lane == 0) mnorm[rr] = fmax(sqrt(s), 1e-12);
  }
  __syncthreads();
  #pragma unroll
  for (int rr = 0; rr < 8; ++rr) {
    double v = bufC[g * 8 + rr][c] / mnorm[g * 8 + rr];
    float vf = (float)v;
    hnf[(size_t)(row0 + rr) * DD + c] = vf;
    hnb[(size_t)(row0 + rr) * DD + c] = f2bf(vf);
  }
}

// ---------------- Kernel 2: sim MFMA loop + ladders + in-loop zeros; keys -> row prefix ----------------
// Byte-identical to R17 (in-loop NT zeros safe here: MFMA consumes loads before
// stores issue; ladder VALU gives slack). Stagger kept.
__global__ __launch_bounds__(1024)
void simloop_kernel(const unsigned short* __restrict__ hnb,
                    float* __restrict__ out) {
  const int t = threadIdx.x, lane = t & 63, wv = t >> 6;   // wv 0..15
  const int m = lane & 15, quad = lane >> 4;
  const int row0 = blockIdx.x * RPB;
  const int it0 = (int)(((blockIdx.x >> 3) * 3u) % NIT);   // same-XCD phase spread

  bf16x8 af0[4], af1[4], af2[4];
  #pragma unroll
  for (int kc = 0; kc < 4; ++kc) {
    af0[kc] = *(const bf16x8*)(hnb + (size_t)(row0 + m) * DD + kc * 32 + quad * 8);
    af1[kc] = *(const bf16x8*)(hnb + (size_t)(row0 + 16 + m) * DD + kc * 32 + quad * 8);
    af2[kc] = *(const bf16x8*)(hnb + (size_t)(row0 + 32 + m) * DD + kc * 32 + quad * 8);
  }

  unsigned LA0[8] = {0,0,0,0,0,0,0,0}, LB0[8] = {0,0,0,0,0,0,0,0};
  unsigned LA1[8] = {0,0,0,0,0,0,0,0}, LB1[8] = {0,0,0,0,0,0,0,0};
  unsigned LA2[8] = {0,0,0,0,0,0,0,0}, LB2[8] = {0,0,0,0,0,0,0,0};

  f32x4* outz = (f32x4*)(out + (size_t)row0 * NN);   // 48 rows = 147456 f32x4
  const f32x4 z = {0.0f, 0.0f, 0.0f, 0.0f};

  for (int itt = 0; itt < NIT; ++itt) {
    int it = itt + it0; if (it >= NIT) it -= NIT;    // staggered column phase
    const int cb = it * (WPL * 32) + wv * 32;
    f32x4 a00 = {0,0,0,0}, a01 = {0,0,0,0};
    f32x4 a10 = {0,0,0,0}, a11 = {0,0,0,0};
    f32x4 a20 = {0,0,0,0}, a21 = {0,0,0,0};
    #pragma unroll
    for (int kc = 0; kc < 4; ++kc) {    // per-kc B loads: caps VGPR for 16-wave block
      bf16x8 b0 = *(const bf16x8*)(hnb + (size_t)(cb + m) * DD + kc * 32 + quad * 8);
      bf16x8 b1 = *(const bf16x8*)(hnb + (size_t)(cb + 16 + m) * DD + kc * 32 + quad * 8);
      a00 = __builtin_amdgcn_mfma_f32_16x16x32_bf16(b0, af0[kc], a00, 0, 0, 0);
      a01 = __builtin_amdgcn_mfma_f32_16x16x32_bf16(b1, af0[kc], a01, 0, 0, 0);
      a10 = __builtin_amdgcn_mfma_f32_16x16x32_bf16(b0, af1[kc], a10, 0, 0, 0);
      a11 = __builtin_amdgcn_mfma_f32_16x16x32_bf16(b1, af1[kc], a11, 0, 0, 0);
      a20 = __builtin_amdgcn_mfma_f32_16x16x32_bf16(b0, af2[kc], a20, 0, 0, 0);
      a21 = __builtin_amdgcn_mfma_f32_16x16x32_bf16(b1, af2[kc], a21, 0, 0, 0);
    }
    // in-loop NT zeros: 48*NN f32 / 24 iters / 1024 thr = 6 f32x4 per thread
    #pragma unroll
    for (int j = 0; j < 6; ++j)
      __builtin_nontemporal_store(z, &outz[it * 6144 + j * 1024 + t]);
    LKEY(a00, LA0, cb)      LKEY(a01, LB0, cb + 16)
    LKEY(a10, LA1, cb)      LKEY(a11, LB1, cb + 16)
    LKEY(a20, LA2, cb)      LKEY(a21, LB2, cb + 16)
  }

  // all zeros of this block retired before key dump overwrites row prefixes
  asm volatile("s_waitcnt vmcnt(0)" ::: "memory");
  __syncthreads();

  const int sbase = (wv * 4 + quad) * 16;   // 64 slots x 16 u32 = 1024 keys/row
  {
    unsigned* d0 = (unsigned*)(out + (size_t)(row0 + m) * NN) + sbase;
    *(uint4*)(d0)     = make_uint4(LA0[0], LA0[1], LA0[2], LA0[3]);
    *(uint4*)(d0 + 4) = make_uint4(LA0[4], LA0[5], LA0[6], LA0[7]);
    *(uint4*)(d0 + 8) = make_uint4(LB0[0], LB0[1], LB0[2], LB0[3]);
    *(uint4*)(d0 + 12)= make_uint4(LB0[4], LB0[5], LB0[6], LB0[7]);
    unsigned* d1 = (unsigned*)(out + (size_t)(row0 + 16 + m) * NN) + sbase;
    *(uint4*)(d1)     = make_uint4(LA1[0], LA1[1], LA1[2], LA1[3]);
    *(uint4*)(d1 + 4) = make_uint4(LA1[4], LA1[5], LA1[6], LA1[7]);
    *(uint4*)(d1 + 8) = make_uint4(LB1[0], LB1[1], LB1[2], LB1[3]);
    *(uint4*)(d1 + 12)= make_uint4(LB1[4], LB1[5], LB1[6], LB1[7]);
    unsigned* d2 = (unsigned*)(out + (size_t)(row0 + 32 + m) * NN) + sbase;
    *(uint4*)(d2)     = make_uint4(LA2[0], LA2[1], LA2[2], LA2[3]);
    *(uint4*)(d2 + 4) = make_uint4(LA2[4], LA2[5], LA2[6], LA2[7]);
    *(uint4*)(d2 + 8) = make_uint4(LB2[0], LB2[1], LB2[2], LB2[3]);
    *(uint4*)(d2 + 12)= make_uint4(LB2[4], LB2[5], LB2[6], LB2[7]);
  }
}

// ---------------- Kernel 3: select + rescore + top-31 + prefix-zero + scatter ----------------
// R18: rescore gathers read fp32 vectors (512 B/row, half of R17). Products of
// fp32 values are EXACT in fp64 (fma((double)a,(double)b,acc)) -> dot is
// deterministic to ~1 ulp fp64 of the true dot of the f32-rounded vectors.
// Ordering margin: rank-31/32 gaps ~1e-3 >> 1e-7 perturbation from f32 rounding.
// Control flow byte-identical to R17; only load types/width changed.
__global__ __launch_bounds__(256)
void select_kernel(const float* __restrict__ hnf, float* __restrict__ out) {
  __shared__ unsigned scand[4][CCAP];
  __shared__ double cres[4][CCAP];
  const int t = threadIdx.x, lane = t & 63, wv = t >> 6;
  const int row = blockIdx.x * 4 + wv;
  float* orow = out + (size_t)row * NN;

  unsigned k16[16];
  {
    const unsigned* src = (const unsigned*)orow + lane * 16;
    #pragma unroll
    for (int q = 0; q < 4; ++q) {
      uint4 a = *(const uint4*)(src + q * 4);
      k16[q * 4 + 0] = a.x; k16[q * 4 + 1] = a.y;
      k16[q * 4 + 2] = a.z; k16[q * 4 + 3] = a.w;
    }
  }

  unsigned lo = 0, hi = 0xFFFFu;
  while (lo < hi) {
    unsigned mid = (lo + hi + 1) >> 1;
    int c = 0;
    #pragma unroll
    for (int i = 0; i < 16; ++i) c += (int)((k16[i] >> 16) >= mid);
    #pragma unroll
    for (int d = 1; d < 64; d <<= 1) c += __shfl_xor(c, d);
    if (c >= TCAND) lo = mid; else hi = mid - 1;
  }
  const unsigned thr = lo;

  int cl = 0;
  #pragma unroll
  for (int i = 0; i < 16; ++i) cl += (int)((k16[i] >> 16) >= thr);
  int pre = cl;
  #pragma unroll
  for (int d = 1; d < 64; d <<= 1) {
    int y = __shfl_up(pre, d);
    if (lane >= d) pre += y;
  }
  const int total = __shfl(pre, 63);
  const int nc = total < CCAP ? total : CCAP;
  int slot = pre - cl;
  #pragma unroll
  for (int i = 0; i < 16; ++i) {
    if ((k16[i] >> 16) >= thr) {
      if (slot < CCAP) scand[wv][slot] = k16[i];
      ++slot;
    }
  }
  // same-wave LDS producer->consumer: compiler inserts lgkmcnt

  // phase 3: 8-candidate-in-flight rescore over fp32 vectors, fp64 accumulate
  const float* arow = hnf + (size_t)row * DD;
  const int g4 = lane >> 4;          // candidate group (0..3)
  const int kl = (lane & 15) * 8;    // this lane's 8-float chunk (32 B)
  float a[8];
  {
    f32x4 a03 = *(const f32x4*)(arow + kl);
    f32x4 a47 = *(const f32x4*)(arow + kl + 4);
    a[0] = a03.x; a[1] = a03.y; a[2] = a03.z; a[3] = a03.w;
    a[4] = a47.x; a[5] = a47.y; a[6] = a47.z; a[7] = a47.w;
  }
  const int ng = (nc + 7) >> 3;      // 2 candidates per group per iteration
  for (int g = 0; g < ng; ++g) {
    const int ci0 = 8 * g + g4;
    const int ci1 = ci0 + 4;
    double p0 = 0.0, p1 = 0.0;
    if (ci0 < nc) {
      const int col = (int)(scand[wv][ci0] & 0xFFFFu);
      const float* brow = hnf + (size_t)col * DD + kl;
      f32x4 b03 = *(const f32x4*)(brow);
      f32x4 b47 = *(const f32x4*)(brow + 4);
      p0 = fma((double)a[0], (double)b03.x, fma((double)a[1], (double)b03.y,
           fma((double)a[2], (double)b03.z, (double)a[3] * (double)b03.w)));
      p0 = fma((double)a[4], (double)b47.x, fma((double)a[5], (double)b47.y,
           fma((double)a[6], (double)b47.z, fma((double)a[7], (double)b47.w, p0))));
    }
    if (ci1 < nc) {
      const int col = (int)(scand[wv][ci1] & 0xFFFFu);
      const float* brow = hnf + (size_t)col * DD + kl;
      f32x4 b03 = *(const f32x4*)(brow);
      f32x4 b47 = *(const f32x4*)(brow + 4);
      p1 = fma((double)a[0], (double)b03.x, fma((double)a[1], (double)b03.y,
           fma((double)a[2], (double)b03.z, (double)a[3] * (double)b03.w)));
      p1 = fma((double)a[4], (double)b47.x, fma((double)a[5], (double)b47.y,
           fma((double)a[6], (double)b47.z, fma((double)a[7], (double)b47.w, p1))));
    }
    #pragma unroll
    for (int d = 1; d < 16; d <<= 1) {
      p0 += __shfl_xor(p0, d);
      p1 += __shfl_xor(p1, d);
    }
    if ((lane & 15) == 0) {
      if (ci0 < nc) cres[wv][ci0] = p0;
      if (ci1 < nc) cres[wv][ci1] = p1;
    }
  }
  double rv0 = -1.0e300, rv1 = -1.0e300;
  int rc0 = 0x7fffffff, rc1 = 0x7fffffff;
  if (lane < nc)      { rv0 = cres[wv][lane];      rc0 = (int)(scand[wv][lane] & 0xFFFFu); }
  if (lane + 64 < nc) { rv1 = cres[wv][lane + 64]; rc1 = (int)(scand[wv][lane + 64] & 0xFFFFu); }

  float fkv = 0.0f; int fkc = 0;
  for (int itk = 0; itk < KTOP; ++itk) {
    bool f = (rv0 > rv1) || (rv0 == rv1 && rc0 < rc1);
    double bv = f ? rv0 : rv1;
    int bc = f ? rc0 : rc1;
    #pragma unroll
    for (int d = 1; d < 64; d <<= 1) {
      double ov = __shfl_xor(bv, d);
      int    oc = __shfl_xor(bc, d);
      bool tk = (ov > bv) || (ov == bv && oc < bc);
      bv = tk ? ov : bv;
      bc = tk ? oc : bc;
    }
    if (lane == itk) { fkv = (float)fmax(bv, 0.0); fkc = bc; }
    if (rv0 == bv && rc0 == bc) rv0 = -1.0e300;
    else if (rv1 == bv && rc1 == bc) rv1 = -1.0e300;
  }

  // re-zero this row's 4 KB key prefix (cols 0-1023), drain, scatter
  {
    f32x4* zp = (f32x4*)orow;
    const f32x4 z = {0.0f, 0.0f, 0.0f, 0.0f};
    #pragma unroll
    for (int j = 0; j < 4; ++j)
      __builtin_nontemporal_store(z, &zp[j * 64 + lane]);
  }
  asm volatile("s_waitcnt vmcnt(0)" ::: "memory");
  if (lane < KTOP) orow[fkc] = fkv;
}

extern "C" void kernel_launch(void* const* d_in, const int* in_sizes, int n_in,
                              void* d_out, int out_size, void* d_ws, size_t ws_size,
                              hipStream_t stream) {
  const float* feat = (const float*)d_in[0];
  const float* W1 = (const float*)d_in[1];
  const float* b1 = (const float*)d_in[2];
  const float* W2 = (const float*)d_in[3];
  const float* b2 = (const float*)d_in[4];
  float* out = (float*)d_out;

  // ws: hnf fp32 (6.3 MB) | hnb bf16 (3.1 MB) | W1T,W2T (128 KB)
  float* hnf = (float*)d_ws;
  unsigned short* hnb = (unsigned short*)(hnf + (size_t)NN * DD);
  float* W1T = (float*)(hnb + (size_t)NN * DD);
  float* W2T = W1T + DD * DD;

  wtrans_kernel<<<DD, DD, 0, stream>>>(W1, W2, W1T, W2T);
  mlp_norm_kernel<<<NN / 16, 256, 0, stream>>>(feat, W1T, b1, W2T, b2, hnf, hnb);
  simloop_kernel<<<NN / RPB, 1024, 0, stream>>>(hnb, out);
  select_kernel<<<NN / 4, 256, 0, stream>>>(hnf, out);
}

// Round 19
// 860.657 us; speedup vs baseline: 1.1321x; 1.0182x over previous
//
#include <hip/hip_runtime.h>
#include <stdint.h>
#include <math.h>

#define NN 12288
#define DD 128
#define KTOP 31
#define TCAND 64         // candidate set >= top-64 by bf16 key (R0-R18-verified margin)
#define CCAP 128         // compaction capacity
#define RPB 48           // rows per loop-block; grid = 256 = 1 block/CU
#define WPL 16           // waves per loop block (1024 threads -> 4 waves/SIMD)
#define NIT 24           // column iterations: 12288 / (WPL*32)
#define KPROW 1024       // keys per row (128 streams x depth 8); 4 KB = row output prefix

typedef __attribute__((ext_vector_type(8))) short bf16x8;
typedef __attribute__((ext_vector_type(4))) float f32x4;

__device__ __forceinline__ unsigned short f2bf(float x) {  // RNE, no NaN in our data
  unsigned int u = __float_as_uint(x);
  u += 0x7fffu + ((u >> 16) & 1u);
  return (unsigned short)(u >> 16);
}

__device__ __forceinline__ unsigned umed3(unsigned a, unsigned b, unsigned c) {
  unsigned d;
  asm("v_med3_u32 %0, %1, %2, %3" : "=v"(d) : "v"(a), "v"(b), "v"(c));
  return d;
}

#define PINS8(Lx, P) { \
  const unsigned p_ = (P); \
  _Pragma("unroll") \
  for (int i_ = 0; i_ < 7; ++i_) \
    Lx[i_] = umed3(p_, Lx[i_], Lx[i_ + 1]); \
  Lx[7] = Lx[7] > p_ ? Lx[7] : p_; }

#define LKEY(ACC, LX, COLBASE) { \
  _Pragma("unroll") \
  for (int r_ = 0; r_ < 4; ++r_) { \
    unsigned bf_ = f2bf((ACC)[r_]); \
    unsigned s_ = (bf_ & 0x8000u) ? 0u : bf_; \
    unsigned p_k = (s_ << 16) | (unsigned)((COLBASE) + quad * 4 + r_); \
    PINS8(LX, p_k) } }

// ---------------- Kernel 0: transpose W1,W2 ----------------
__global__ __launch_bounds__(128)
void wtrans_kernel(const float* __restrict__ W1, const float* __restrict__ W2,
                   float* __restrict__ W1T, float* __restrict__ W2T) {
  const int r = blockIdx.x, c = threadIdx.x;
  W1T[(size_t)c * DD + r] = W1[(size_t)r * DD + c];
  W2T[(size_t)c * DD + r] = W2[(size_t)r * DD + c];
}

// ---------------- Kernel 1: MLP + L2 normalize ----------------
// R19: bufB (post-ReLU) stored f32 -> layer-2 reads f32x4 per 4 k-steps: LDS
// reads/thread 768 -> 512 (modeled 46 -> 31 us LDS-throughput term). Reference
// is fp32 end-to-end; f32-rounding of ReLU outputs perturbs results ~1e-7
// relative vs 4e-3 tolerance / 1e-3 selection gaps. Accumulation ORDER kept
// (k ascending). fp64 FMA chain otherwise unchanged.
__global__ __launch_bounds__(256)
void mlp_norm_kernel(const float* __restrict__ feat,
                     const float* __restrict__ W1T, const float* __restrict__ b1,
                     const float* __restrict__ W2T, const float* __restrict__ b2,
                     float* __restrict__ hnf, unsigned short* __restrict__ hnb) {
  __shared__ float  bufA[16][DD];    // 8 KB (f32 input, exact)
  __shared__ float  bufB[16][DD];    // 8 KB (f32 post-ReLU)
  __shared__ double bufC[16][DD];    // 16 KB
  __shared__ double mnorm[16];
  const int t = threadIdx.x;
  const int c = t & 127;
  const int g = t >> 7;
  const int row0 = blockIdx.x * 16 + g * 8;

  #pragma unroll
  for (int rr = 0; rr < 8; ++rr)
    bufA[g * 8 + rr][c] = feat[(size_t)(row0 + rr) * DD + c];
  __syncthreads();

  {
    double acc[8] = {0,0,0,0,0,0,0,0};
    for (int k = 0; k < DD; k += 4) {
      double w0 = (double)W1T[(size_t)k * DD + c];
      double w1 = (double)W1T[(size_t)(k + 1) * DD + c];
      double w2 = (double)W1T[(size_t)(k + 2) * DD + c];
      double w3 = (double)W1T[(size_t)(k + 3) * DD + c];
      #pragma unroll
      for (int rr = 0; rr < 8; ++rr) {
        f32x4 a4 = *(const f32x4*)(&bufA[g * 8 + rr][k]);
        acc[rr] = fma(w0, (double)a4.x, acc[rr]);
        acc[rr] = fma(w1, (double)a4.y, acc[rr]);
        acc[rr] = fma(w2, (double)a4.z, acc[rr]);
        acc[rr] = fma(w3, (double)a4.w, acc[rr]);
      }
    }
    double bb = (double)b1[c];
    #pragma unroll
    for (int rr = 0; rr < 8; ++rr)
      bufB[g * 8 + rr][c] = (float)fmax(acc[rr] + bb, 0.0);
  }
  __syncthreads();
  {
    double acc[8] = {0,0,0,0,0,0,0,0};
    for (int k = 0; k < DD; k += 4) {
      double w0 = (double)W2T[(size_t)k * DD + c];
      double w1 = (double)W2T[(size_t)(k + 1) * DD + c];
      double w2 = (double)W2T[(size_t)(k + 2) * DD + c];
      double w3 = (double)W2T[(size_t)(k + 3) * DD + c];
      #pragma unroll
      for (int rr = 0; rr < 8; ++rr) {
        f32x4 a4 = *(const f32x4*)(&bufB[g * 8 + rr][k]);
        acc[rr] = fma(w0, (double)a4.x, acc[rr]);
        acc[rr] = fma(w1, (double)a4.y, acc[rr]);
        acc[rr] = fma(w2, (double)a4.z, acc[rr]);
        acc[rr] = fma(w3, (double)a4.w, acc[rr]);
      }
    }
    double bb = (double)b2[c];
    #pragma unroll
    for (int rr = 0; rr < 8; ++rr)
      bufC[g * 8 + rr][c] = acc[rr] + bb;
  }
  __syncthreads();

  const int lane = t & 63;
  const int w = t >> 6;
  #pragma unroll
  for (int r2 = 0; r2 < 4; ++r2) {
    int rr = w * 4 + r2;
    double x0 = bufC[rr][lane];
    double x1 = bufC[rr][lane + 64];
    double s = x0 * x0 + x1 * x1;
    #pragma unroll
    for (int d = 1; d < 64; d <<= 1)
      s += __shfl_xor(s, d);
    if (lane == 0) mnorm[rr] = fmax(sqrt(s), 1e-12);
  }
  __syncthreads();
  #pragma unroll
  for (int rr = 0; rr < 8; ++rr) {
    double v = bufC[g * 8 + rr][c] / mnorm[g * 8 + rr];
    float vf = (float)v;
    hnf[(size_t)(row0 + rr) * DD + c] = vf;
    hnb[(size_t)(row0 + rr) * DD + c] = f2bf(vf);
  }
}

// ---------------- Kernel 2: sim MFMA loop + ladders + in-loop zeros; keys -> row prefix ----------------
// R19: prefix region (cols 0-1023 of each row) is NEVER zeroed here — those
// zeros were dead (keys overwrite them; select re-zeros after reading). The
// skip predicate is iteration-invariant: unit u = it*6144 + j*1024 + t has
// u%3072 = j*1024+t (mod 3072) -> prefix iff (j==0||j==3) && t<256. With no
// zero/key aliasing, the pre-dump vmcnt(0)+barrier is deleted. -25 MB writes.
__global__ __launch_bounds__(1024)
void simloop_kernel(const unsigned short* __restrict__ hnb,
                    float* __restrict__ out) {
  const int t = threadIdx.x, lane = t & 63, wv = t >> 6;   // wv 0..15
  const int m = lane & 15, quad = lane >> 4;
  const int row0 = blockIdx.x * RPB;
  const int it0 = (int)(((blockIdx.x >> 3) * 3u) % NIT);   // same-XCD phase spread
  const bool pfx = (t < 256);                              // prefix-owning threads

  bf16x8 af0[4], af1[4], af2[4];
  #pragma unroll
  for (int kc = 0; kc < 4; ++kc) {
    af0[kc] = *(const bf16x8*)(hnb + (size_t)(row0 + m) * DD + kc * 32 + quad * 8);
    af1[kc] = *(const bf16x8*)(hnb + (size_t)(row0 + 16 + m) * DD + kc * 32 + quad * 8);
    af2[kc] = *(const bf16x8*)(hnb + (size_t)(row0 + 32 + m) * DD + kc * 32 + quad * 8);
  }

  unsigned LA0[8] = {0,0,0,0,0,0,0,0}, LB0[8] = {0,0,0,0,0,0,0,0};
  unsigned LA1[8] = {0,0,0,0,0,0,0,0}, LB1[8] = {0,0,0,0,0,0,0,0};
  unsigned LA2[8] = {0,0,0,0,0,0,0,0}, LB2[8] = {0,0,0,0,0,0,0,0};

  f32x4* outz = (f32x4*)(out + (size_t)row0 * NN);   // 48 rows = 147456 f32x4
  const f32x4 z = {0.0f, 0.0f, 0.0f, 0.0f};

  for (int itt = 0; itt < NIT; ++itt) {
    int it = itt + it0; if (it >= NIT) it -= NIT;    // staggered column phase
    const int cb = it * (WPL * 32) + wv * 32;
    f32x4 a00 = {0,0,0,0}, a01 = {0,0,0,0};
    f32x4 a10 = {0,0,0,0}, a11 = {0,0,0,0};
    f32x4 a20 = {0,0,0,0}, a21 = {0,0,0,0};
    #pragma unroll
    for (int kc = 0; kc < 4; ++kc) {    // per-kc B loads: caps VGPR for 16-wave block
      bf16x8 b0 = *(const bf16x8*)(hnb + (size_t)(cb + m) * DD + kc * 32 + quad * 8);
      bf16x8 b1 = *(const bf16x8*)(hnb + (size_t)(cb + 16 + m) * DD + kc * 32 + quad * 8);
      a00 = __builtin_amdgcn_mfma_f32_16x16x32_bf16(b0, af0[kc], a00, 0, 0, 0);
      a01 = __builtin_amdgcn_mfma_f32_16x16x32_bf16(b1, af0[kc], a01, 0, 0, 0);
      a10 = __builtin_amdgcn_mfma_f32_16x16x32_bf16(b0, af1[kc], a10, 0, 0, 0);
      a11 = __builtin_amdgcn_mfma_f32_16x16x32_bf16(b1, af1[kc], a11, 0, 0, 0);
      a20 = __builtin_amdgcn_mfma_f32_16x16x32_bf16(b0, af2[kc], a20, 0, 0, 0);
      a21 = __builtin_amdgcn_mfma_f32_16x16x32_bf16(b1, af2[kc], a21, 0, 0, 0);
    }
    // in-loop NT zeros (6 f32x4/thread/iter); j==0 and j==3 land on row
    // prefixes for t<256 — skipped (keys own those bytes; select re-zeros).
    if (!pfx) __builtin_nontemporal_store(z, &outz[it * 6144 + t]);
    __builtin_nontemporal_store(z, &outz[it * 6144 + 1024 + t]);
    __builtin_nontemporal_store(z, &outz[it * 6144 + 2048 + t]);
    if (!pfx) __builtin_nontemporal_store(z, &outz[it * 6144 + 3072 + t]);
    __builtin_nontemporal_store(z, &outz[it * 6144 + 4096 + t]);
    __builtin_nontemporal_store(z, &outz[it * 6144 + 5120 + t]);
    LKEY(a00, LA0, cb)      LKEY(a01, LB0, cb + 16)
    LKEY(a10, LA1, cb)      LKEY(a11, LB1, cb + 16)
    LKEY(a20, LA2, cb)      LKEY(a21, LB2, cb + 16)
  }

  // key dump: no aliasing with the zero stream (prefix never zeroed) -> no
  // drain, no barrier; kernel-end drains everything before select launches.
  const int sbase = (wv * 4 + quad) * 16;   // 64 slots x 16 u32 = 1024 keys/row
  {
    unsigned* d0 = (unsigned*)(out + (size_t)(row0 + m) * NN) + sbase;
    *(uint4*)(d0)     = make_uint4(LA0[0], LA0[1], LA0[2], LA0[3]);
    *(uint4*)(d0 + 4) = make_uint4(LA0[4], LA0[5], LA0[6], LA0[7]);
    *(uint4*)(d0 + 8) = make_uint4(LB0[0], LB0[1], LB0[2], LB0[3]);
    *(uint4*)(d0 + 12)= make_uint4(LB0[4], LB0[5], LB0[6], LB0[7]);
    unsigned* d1 = (unsigned*)(out + (size_t)(row0 + 16 + m) * NN) + sbase;
    *(uint4*)(d1)     = make_uint4(LA1[0], LA1[1], LA1[2], LA1[3]);
    *(uint4*)(d1 + 4) = make_uint4(LA1[4], LA1[5], LA1[6], LA1[7]);
    *(uint4*)(d1 + 8) = make_uint4(LB1[0], LB1[1], LB1[2], LB1[3]);
    *(uint4*)(d1 + 12)= make_uint4(LB1[4], LB1[5], LB1[6], LB1[7]);
    unsigned* d2 = (unsigned*)(out + (size_t)(row0 + 32 + m) * NN) + sbase;
    *(uint4*)(d2)     = make_uint4(LA2[0], LA2[1], LA2[2], LA2[3]);
    *(uint4*)(d2 + 4) = make_uint4(LA2[4], LA2[5], LA2[6], LA2[7]);
    *(uint4*)(d2 + 8) = make_uint4(LB2[0], LB2[1], LB2[2], LB2[3]);
    *(uint4*)(d2 + 12)= make_uint4(LB2[4], LB2[5], LB2[6], LB2[7]);
  }
}

// ---------------- Kernel 3: select + rescore + top-31 + prefix-zero + scatter ----------------
// Byte-identical to R18 (fp32 gathers, 8 candidates in flight, fp64 accumulate).
__global__ __launch_bounds__(256)
void select_kernel(const float* __restrict__ hnf, float* __restrict__ out) {
  __shared__ unsigned scand[4][CCAP];
  __shared__ double cres[4][CCAP];
  const int t = threadIdx.x, lane = t & 63, wv = t >> 6;
  const int row = blockIdx.x * 4 + wv;
  float* orow = out + (size_t)row * NN;

  unsigned k16[16];
  {
    const unsigned* src = (const unsigned*)orow + lane * 16;
    #pragma unroll
    for (int q = 0; q < 4; ++q) {
      uint4 a = *(const uint4*)(src + q * 4);
      k16[q * 4 + 0] = a.x; k16[q * 4 + 1] = a.y;
      k16[q * 4 + 2] = a.z; k16[q * 4 + 3] = a.w;
    }
  }

  unsigned lo = 0, hi = 0xFFFFu;
  while (lo < hi) {
    unsigned mid = (lo + hi + 1) >> 1;
    int c = 0;
    #pragma unroll
    for (int i = 0; i < 16; ++i) c += (int)((k16[i] >> 16) >= mid);
    #pragma unroll
    for (int d = 1; d < 64; d <<= 1) c += __shfl_xor(c, d);
    if (c >= TCAND) lo = mid; else hi = mid - 1;
  }
  const unsigned thr = lo;

  int cl = 0;
  #pragma unroll
  for (int i = 0; i < 16; ++i) cl += (int)((k16[i] >> 16) >= thr);
  int pre = cl;
  #pragma unroll
  for (int d = 1; d < 64; d <<= 1) {
    int y = __shfl_up(pre, d);
    if (lane >= d) pre += y;
  }
  const int total = __shfl(pre, 63);
  const int nc = total < CCAP ? total : CCAP;
  int slot = pre - cl;
  #pragma unroll
  for (int i = 0; i < 16; ++i) {
    if ((k16[i] >> 16) >= thr) {
      if (slot < CCAP) scand[wv][slot] = k16[i];
      ++slot;
    }
  }
  // same-wave LDS producer->consumer: compiler inserts lgkmcnt

  // phase 3: 8-candidate-in-flight rescore over fp32 vectors, fp64 accumulate
  const float* arow = hnf + (size_t)row * DD;
  const int g4 = lane >> 4;          // candidate group (0..3)
  const int kl = (lane & 15) * 8;    // this lane's 8-float chunk (32 B)
  float a[8];
  {
    f32x4 a03 = *(const f32x4*)(arow + kl);
    f32x4 a47 = *(const f32x4*)(arow + kl + 4);
    a[0] = a03.x; a[1] = a03.y; a[2] = a03.z; a[3] = a03.w;
    a[4] = a47.x; a[5] = a47.y; a[6] = a47.z; a[7] = a47.w;
  }
  const int ng = (nc + 7) >> 3;      // 2 candidates per group per iteration
  for (int g = 0; g < ng; ++g) {
    const int ci0 = 8 * g + g4;
    const int ci1 = ci0 + 4;
    double p0 = 0.0, p1 = 0.0;
    if (ci0 < nc) {
      const int col = (int)(scand[wv][ci0] & 0xFFFFu);
      const float* brow = hnf + (size_t)col * DD + kl;
      f32x4 b03 = *(const f32x4*)(brow);
      f32x4 b47 = *(const f32x4*)(brow + 4);
      p0 = fma((double)a[0], (double)b03.x, fma((double)a[1], (double)b03.y,
           fma((double)a[2], (double)b03.z, (double)a[3] * (double)b03.w)));
      p0 = fma((double)a[4], (double)b47.x, fma((double)a[5], (double)b47.y,
           fma((double)a[6], (double)b47.z, fma((double)a[7], (double)b47.w, p0))));
    }
    if (ci1 < nc) {
      const int col = (int)(scand[wv][ci1] & 0xFFFFu);
      const float* brow = hnf + (size_t)col * DD + kl;
      f32x4 b03 = *(const f32x4*)(brow);
      f32x4 b47 = *(const f32x4*)(brow + 4);
      p1 = fma((double)a[0], (double)b03.x, fma((double)a[1], (double)b03.y,
           fma((double)a[2], (double)b03.z, (double)a[3] * (double)b03.w)));
      p1 = fma((double)a[4], (double)b47.x, fma((double)a[5], (double)b47.y,
           fma((double)a[6], (double)b47.z, fma((double)a[7], (double)b47.w, p1))));
    }
    #pragma unroll
    for (int d = 1; d < 16; d <<= 1) {
      p0 += __shfl_xor(p0, d);
      p1 += __shfl_xor(p1, d);
    }
    if ((lane & 15) == 0) {
      if (ci0 < nc) cres[wv][ci0] = p0;
      if (ci1 < nc) cres[wv][ci1] = p1;
    }
  }
  double rv0 = -1.0e300, rv1 = -1.0e300;
  int rc0 = 0x7fffffff, rc1 = 0x7fffffff;
  if (lane < nc)      { rv0 = cres[wv][lane];      rc0 = (int)(scand[wv][lane] & 0xFFFFu); }
  if (lane + 64 < nc) { rv1 = cres[wv][lane + 64]; rc1 = (int)(scand[wv][lane + 64] & 0xFFFFu); }

  float fkv = 0.0f; int fkc = 0;
  for (int itk = 0; itk < KTOP; ++itk) {
    bool f = (rv0 > rv1) || (rv0 == rv1 && rc0 < rc1);
    double bv = f ? rv0 : rv1;
    int bc = f ? rc0 : rc1;
    #pragma unroll
    for (int d = 1; d < 64; d <<= 1) {
      double ov = __shfl_xor(bv, d);
      int    oc = __shfl_xor(bc, d);
      bool tk = (ov > bv) || (ov == bv && oc < bc);
      bv = tk ? ov : bv;
      bc = tk ? oc : bc;
    }
    if (lane == itk) { fkv = (float)fmax(bv, 0.0); fkc = bc; }
    if (rv0 == bv && rc0 == bc) rv0 = -1.0e300;
    else if (rv1 == bv && rc1 == bc) rv1 = -1.0e300;
  }

  // re-zero this row's 4 KB key prefix (cols 0-1023), drain, scatter
  {
    f32x4* zp = (f32x4*)orow;
    const f32x4 z = {0.0f, 0.0f, 0.0f, 0.0f};
    #pragma unroll
    for (int j = 0; j < 4; ++j)
      __builtin_nontemporal_store(z, &zp[j * 64 + lane]);
  }
  asm volatile("s_waitcnt vmcnt(0)" ::: "memory");
  if (lane < KTOP) orow[fkc] = fkv;
}

extern "C" void kernel_launch(void* const* d_in, const int* in_sizes, int n_in,
                              void* d_out, int out_size, void* d_ws, size_t ws_size,
                              hipStream_t stream) {
  const float* feat = (const float*)d_in[0];
  const float* W1 = (const float*)d_in[1];
  const float* b1 = (const float*)d_in[2];
  const float* W2 = (const float*)d_in[3];
  const float* b2 = (const float*)d_in[4];
  float* out = (float*)d_out;

  // ws: hnf fp32 (6.3 MB) | hnb bf16 (3.1 MB) | W1T,W2T (128 KB)
  float* hnf = (float*)d_ws;
  unsigned short* hnb = (unsigned short*)(hnf + (size_t)NN * DD);
  float* W1T = (float*)(hnb + (size_t)NN * DD);
  float* W2T = W1T + DD * DD;

  wtrans_kernel<<<DD, DD, 0, stream>>>(W1, W2, W1T, W2T);
  mlp_norm_kernel<<<NN / 16, 256, 0, stream>>>(feat, W1T, b1, W2T, b2, hnf, hnb);
  simloop_kernel<<<NN / RPB, 1024, 0, stream>>>(hnb, out);
  select_kernel<<<NN / 4, 256, 0, stream>>>(hnf, out);
}